// Round 8
// baseline (2791.462 us; speedup 1.0000x reference)
//
#include <hip/hip_runtime.h>
#include <math.h>

// ---------------------------------------------------------------------------
// FNO_multi: B=4, V=3, S=256x256, TIN=10, WIDTH=32, M1=M2=16, NL=6, VOUT=3, STEP=10
// rfft2/irfft2 -> truncated DFT matmuls. All fp32.
// Scratch in d_out (T / T2B / XF, dead before k_final). Per-layer m1-fold in ws.
// Conv + final use SCALAR uniform reads (s_load + SGPR-operand FMA codegen),
// which R5/R6 A/B showed beats explicit float4 vector loads for uniform data.
// Activations: [B][C=32][V][256][256].
// ---------------------------------------------------------------------------

// ws offsets (floats); total = 53,530,624 floats = 214.1 MB (< 217.25 proven)
#define OFF_A   0
#define OFF_B   25165824
#define OFF_T1  50331648   // tabF [m=128][g=8][4]                 (4096)
#define OFF_T2T 50335744   // tab2 [n=256][kx=32][2]               (16384)
#define OFF_TCS 50352128   // tcs  [kx=32][n=256][2]               (16384)
#define OFF_TB  50368512   // tabB [j=32][m=256]                   (8192)
#define OFF_WT  50376704   // w1tT [u=256][c=32]                   (8192)
#define OFF_FL  50384896   // per-layer folded weights: fp1,fp2 (2x1572864)

// d_out scratch offsets (floats); total = 7,864,320 = out_size exactly
#define DO_T    0          // forward-T [b,c,v,n] x 32             (3145728)
#define DO_T2B  3145728    // T2B per-(b,v,n)-contiguous rows      (3145728)
#define DO_XF   6291456    // 4 partial XF buffers x 393216        (1572864)

// fast gelu: exact-erf form via A&S 7.1.26 (|eps_erf| <= ~1.5e-7)
__device__ __forceinline__ float geluf(float x) {
    float a = fabsf(x) * 0.70710678118654752f;
    float t = __builtin_amdgcn_rcpf(fmaf(0.3275911f, a, 1.0f));
    float p = t * fmaf(t, fmaf(t, fmaf(t, fmaf(t, 1.061405429f, -1.453152027f),
                                       1.421413741f), -0.284496736f), 0.254829592f);
    float e = __expf(-a * a);
    float erfa = fmaf(-p, e, 1.0f);
    float er = copysignf(erfa, x);
    return 0.5f * x * (1.0f + er);
}

__global__ void k_init_tables(float* __restrict__ ws, const float* __restrict__ w1t) {
    const float W0 = 6.2831853071795864769f / 256.0f;
    int stride = gridDim.x * blockDim.x;
    int tid = blockIdx.x * blockDim.x + threadIdx.x;
    for (int i = tid; i < 4096; i += stride) {          // tabF (folded fwd y-DFT)
        int m = i >> 5, q = i & 31, g = q >> 2, j = q & 3;
        int k0 = 4 * (g & 3) + (g >> 2);
        int k = k0 + 2 * (j >> 1);
        float th = W0 * (float)((k * m) & 255);
        ws[OFF_T1 + i] = (j & 1) ? -sinf(th) : cosf(th);
    }
    for (int idx = tid; idx < 8192; idx += stride) {    // tab2 (fwd x) [n][kx][2]
        int n = idx >> 5, kx = idx & 31;
        int KX = (kx < 16) ? kx : (kx + 224);
        float th = W0 * (float)((KX * n) & 255);
        ws[OFF_T2T + 2*idx]     = cosf(th);
        ws[OFF_T2T + 2*idx + 1] = sinf(th);
    }
    for (int idx = tid; idx < 8192; idx += stride) {    // tcs (inv x) [kx][n][2]
        int kx = idx >> 8, n = idx & 255;
        int KX = (kx < 16) ? kx : (kx + 224);
        float th = W0 * (float)((KX * n) & 255);
        ws[OFF_TCS + 2*idx]     = cosf(th);
        ws[OFF_TCS + 2*idx + 1] = sinf(th);
    }
    for (int idx = tid; idx < 8192; idx += stride) {    // tabB (inv y, scaled)
        int j = idx >> 8, m = idx & 255, k = j >> 1;
        float th = W0 * (float)((k * m) & 255);
        float beta = (k == 0) ? (1.0f/65536.0f) : (2.0f/65536.0f);
        float val;
        if (j & 1) val = (k == 0) ? 0.0f : -beta * sinf(th);
        else       val = beta * cosf(th);
        ws[OFF_TB + idx] = val;
    }
    for (int idx = tid; idx < 8192; idx += stride)      // w1tT[u][c]
        ws[OFF_WT + idx] = w1t[(idx & 31) * 256 + (idx >> 5)];
}

// per-layer fold of m1 into spectral weights (interleaved r,i):
// F[i,op,v,p] = sum_o m1w[op,o] * W[i,o,v,p]
__global__ __launch_bounds__(256) void k_foldw(const float* __restrict__ w1r_l,
                                               const float* __restrict__ w1i_l,
                                               const float* __restrict__ w2r_l,
                                               const float* __restrict__ w2i_l,
                                               const float* __restrict__ m1w_l,
                                               float2* __restrict__ fp1,
                                               float2* __restrict__ fp2) {
    int blk = blockIdx.x;            // i*32 + op
    int p = threadIdx.x;
    int op = blk & 31; int i = blk >> 5;
    const float* mrow = m1w_l + op*32;
#pragma unroll
    for (int v = 0; v < 3; ++v) {
        float a1r = 0.f, a1i = 0.f, a2r = 0.f, a2i = 0.f;
#pragma unroll 4
        for (int o = 0; o < 32; ++o) {
            float mw = mrow[o];
            size_t idx = ((size_t)(i*32 + o)*3 + v)*256 + p;
            a1r = fmaf(mw, w1r_l[idx], a1r); a1i = fmaf(mw, w1i_l[idx], a1i);
            a2r = fmaf(mw, w2r_l[idx], a2r); a2i = fmaf(mw, w2i_l[idx], a2i);
        }
        size_t oidx = ((size_t)(i*32 + op)*3 + v)*256 + p;
        float2 u1; u1.x = a1r; u1.y = a1i;
        float2 u2; u2.x = a2r; u2.y = a2i;
        fp1[oidx] = u1; fp2[oidx] = u2;
    }
}

// radix-2 fold in LDS
__device__ __forceinline__ void fold_lds(float* lds, int tid) {
#pragma unroll
    for (int it = 0; it < 16; ++it) {
        int pi = it * 256 + tid;
        int r = pi >> 7, mm = pi & 127;
        float* row = lds + r * 257;
        float a = row[mm], c = row[mm + 128];
        row[mm] = a + c; row[mm + 128] = a - c;
    }
}

// forward y-DFT from folded LDS rows -> forward-T
__device__ __forceinline__ void dft_row_phase(const float* lds, const float* __restrict__ tabF,
                                              float* __restrict__ T, int b, int v, int n, int tid) {
    int r = tid >> 3, g = tid & 7;
    int p = g >> 2, idx = g & 3;
    const float* dp = lds + r * 257 + p * 128;
    const float* tp = tabF + g * 4;
    float a0 = 0.f, a1 = 0.f, a2 = 0.f, a3 = 0.f;
#pragma unroll 4
    for (int m = 0; m < 128; ++m) {
        float d = dp[m];
        float4 t = *(const float4*)(tp + m * 32);
        a0 += d * t.x; a1 += d * t.y; a2 += d * t.z; a3 += d * t.w;
    }
    size_t trow = ((size_t)((b * 32 + r) * 3 + v) * 256 + n) * 32;
    float2 w0; w0.x = a0; w0.y = a1;
    float2 w1; w1.x = a2; w1.y = a3;
    *(float2*)(T + trow + 8 * idx + 2 * p) = w0;
    *(float2*)(T + trow + 8 * idx + 2 * p + 4) = w1;
}

// fc0 + fused y-DFT
__global__ __launch_bounds__(256) void k_fc0(const float* __restrict__ x,
                                             const float* __restrict__ w,
                                             const float* __restrict__ bias,
                                             float* __restrict__ outA,
                                             float* __restrict__ T,
                                             const float* __restrict__ tabF) {
    __shared__ float lds[32 * 257];
    int blk = blockIdx.x;           // (b*3+v)*256 + n
    int m = threadIdx.x;
    int n = blk & 255;
    int bv = blk >> 8;
    int v = bv % 3, b = bv / 3;
    const float* xp = x + ((size_t)blk * 256 + m) * 10;
    float xin[10];
#pragma unroll
    for (int t = 0; t < 10; t++) xin[t] = xp[t];
    float gx = (float)n * (1.0f/255.0f), gy = (float)m * (1.0f/255.0f);
    float* op = outA + ((size_t)(b*96) + v) * 65536 + n * 256 + m;
#pragma unroll
    for (int c = 0; c < 32; c++) {
        float a = bias[c] + gx * w[10*32 + c] + gy * w[11*32 + c];
#pragma unroll
        for (int t = 0; t < 10; t++) a += xin[t] * w[t*32 + c];
        op[(size_t)c * 196608] = a;
        lds[c * 257 + m] = a;
    }
    __syncthreads();
    fold_lds(lds, m);
    __syncthreads();
    dft_row_phase(lds, tabF, T, b, v, n, m);
}

// forward x-DFT, 4-way n-reduction split -> partial XF buffers
__global__ __launch_bounds__(256) void k_dft_x(const float* __restrict__ T,
                                               float* __restrict__ XFp,
                                               const float* __restrict__ tab2) {
    __shared__ float lds[2048];
    int idx = blockIdx.x;
    int part = idx & 3; int blk = idx >> 2;   // blk = bv*32 + i
    int i = blk & 31; int bv = blk >> 5;
    int b = bv / 3, v = bv - 3*b;
    int tid = threadIdx.x;
    const float4* slab = (const float4*)(T + (size_t)((b*32 + i)*3 + v) * 8192 + part * 2048);
#pragma unroll
    for (int j = 0; j < 2; ++j)
        ((float4*)lds)[j * 256 + tid] = slab[j * 256 + tid];
    __syncthreads();
    int ky = tid & 15, kxh = tid >> 4;
    const float* t2b = tab2 + part * 4096;
    float r0=0.f, i0=0.f, r1=0.f, i1=0.f;
#pragma unroll 2
    for (int nn = 0; nn < 64; nn++) {
        float2 t = *(const float2*)(lds + nn * 32 + 2 * ky);
        float2 cs0 = *(const float2*)(t2b + nn*64 + kxh*2);
        float2 cs1 = *(const float2*)(t2b + nn*64 + (kxh+16)*2);
        r0 += t.x*cs0.x + t.y*cs0.y;  i0 += t.y*cs0.x - t.x*cs0.y;
        r1 += t.x*cs1.x + t.y*cs1.y;  i1 += t.y*cs1.x - t.x*cs1.y;
    }
    float2* xfp = (float2*)(XFp + (size_t)part * 393216 + (size_t)blk * 1024);
    float2 v0; v0.x = r0; v0.y = i0;
    float2 v1; v1.x = r1; v1.y = i1;
    xfp[kxh*16 + ky] = v0;
    xfp[(kxh+16)*16 + ky] = v1;
}

// channel mix (folded weights, sums 4 XF partials) + inverse x-DFT (4-way n split).
// Writes T2B per-(b,v,n)-contiguous: T2B[bv*262144 + n*1024 + o*32 + ky2]
__global__ __launch_bounds__(256) void k_mixidft(const float* __restrict__ XFp,
                                                 float* __restrict__ T2B,
                                                 const float2* __restrict__ fp1,
                                                 const float2* __restrict__ fp2,
                                                 const float2* __restrict__ tcs) {
    __shared__ float Olds[2048];
    int idx = blockIdx.x;
    int part = idx & 3; int blk = idx >> 2;   // blk = bv*32 + o
    int o = blk & 31; int bv = blk >> 5;
    int b = bv / 3, v = bv - 3*b;
    int tid = threadIdx.x;
    {
        int ky = tid & 15, kxh = tid >> 4;
        float R0=0.f, I0=0.f, R1=0.f, I1=0.f;
#pragma unroll 4
        for (int i = 0; i < 32; i++) {
            size_t xbase = (size_t)(bv*32 + i) * 1024;
            float x0r=0.f, x0i=0.f, x1r=0.f, x1i=0.f;
#pragma unroll
            for (int p = 0; p < 4; p++) {
                const float2* xp = (const float2*)(XFp + (size_t)p * 393216 + xbase);
                float2 a = xp[kxh*16 + ky];
                float2 c = xp[(kxh+16)*16 + ky];
                x0r += a.x; x0i += a.y; x1r += c.x; x1i += c.y;
            }
            size_t wbase = ((size_t)(i*32 + o)*3 + v) * 256;
            float2 u1 = fp1[wbase + tid];
            float2 u2 = fp2[wbase + tid];
            R0 += x0r*u1.x - x0i*u1.y;  I0 += x0r*u1.y + x0i*u1.x;
            R1 += x1r*u2.x - x1i*u2.y;  I1 += x1r*u2.y + x1i*u2.x;
        }
        float2 v0; v0.x = R0; v0.y = I0;
        float2 v1; v1.x = R1; v1.y = I1;
        ((float2*)Olds)[kxh*16 + ky] = v0;
        ((float2*)Olds)[(kxh+16)*16 + ky] = v1;
    }
    __syncthreads();
    {
        int ky2 = tid & 31, n8 = tid >> 5;
        int ky = ky2 >> 1, ri = ky2 & 1;
        float* base = T2B + (size_t)bv * 262144 + o*32;
#pragma unroll 2
        for (int ii = 0; ii < 8; ++ii) {
            int n = part*64 + ii*8 + n8;
            float acc = 0.f;
#pragma unroll
            for (int kx = 0; kx < 32; ++kx) {
                float2 ov = ((const float2*)Olds)[kx*16 + ky];
                float2 cs = tcs[kx*256 + n];
                float ca = ri ? cs.y : cs.x;
                float cb = ri ? cs.x : -cs.y;
                acc += ov.x*ca + ov.y*cb;
            }
            base[(size_t)n*1024 + ky2] = acc;
        }
    }
}

// fused: inverse y-DFT (T2B premixed rows, SCALAR uniform reads) + gelu +
// m2/ww conv + optional skip + fused next-layer y-DFT.
template<int HAS_SKIP, int DO_DFT>
__global__ __launch_bounds__(256) void k_conv(
    const float* IN, float* OUT, const float* SK,
    const float* __restrict__ T2B, const float* __restrict__ tabB,
    const float* __restrict__ m1b,
    const float* __restrict__ m2w, const float* __restrict__ m2b,
    const float* __restrict__ ww,  const float* __restrict__ wb,
    const float* __restrict__ bw,  const float* __restrict__ bb,
    float* __restrict__ Tout, const float* __restrict__ tabF, int l)
{
    __shared__ float lds[DO_DFT ? 32 * 257 : 1];
    int blk = blockIdx.x;            // (b*3+v)*256 + n
    int m = threadIdx.x;
    int n = blk & 255; int bv = blk >> 8;
    int b = bv / 3, v = bv - 3*b;

    // ---- tb (per-thread inverse-y column) + early h loads
    float tb[32];
#pragma unroll
    for (int j = 0; j < 32; j++) tb[j] = tabB[j*256 + m];
    const float* inp = IN + (size_t)(b*96 + v) * 65536 + n * 256 + m;
    float hv[32];
#pragma unroll
    for (int c = 0; c < 32; c++) hv[c] = inp[(size_t)c * 196608];

    // ---- Phase A: inverse y-DFT of premixed rows + m1b + gelu -> g1
    const float* t2row = T2B + (size_t)bv * 262144 + (size_t)n * 1024;
    const float* m1bl = m1b + l*32;
    float g1[32];
#pragma unroll
    for (int o = 0; o < 32; o++) {
        const float* tp = t2row + o*32;
        float a = m1bl[o];
#pragma unroll
        for (int j = 0; j < 32; j++) a = fmaf(tp[j], tb[j], a);
        g1[o] = geluf(a);
    }

    // ---- Phase C: per-o m2.g1 + ww.hv + bias, gelu, store (+DFT stage)
    const float* m2wl = m2w + l*1024; const float* m2bl = m2b + l*32;
    const float* wwl  = ww  + l*1024; const float* wbl  = wb  + l*32;
    const float* bwl  = bw  + l*64;   const float* bbl  = bb  + l*32;
    float gx = (float)n * (1.0f/255.0f), gy = (float)m * (1.0f/255.0f);
    float* outp = OUT + (size_t)(b*96 + v) * 65536 + n * 256 + m;
    const float* skp = SK + (size_t)(b*96 + v) * 65536 + n * 256 + m;

#pragma unroll
    for (int o = 0; o < 32; o++) {
        float a = m2bl[o] + wbl[o] + bbl[o] + bwl[o*2]*gx + bwl[o*2+1]*gy;
#pragma unroll
        for (int c = 0; c < 32; c++) a = fmaf(m2wl[o*32 + c], g1[c], a);
#pragma unroll
        for (int c = 0; c < 32; c++) a = fmaf(wwl[o*32 + c], hv[c], a);
        float val = geluf(a);
        if (HAS_SKIP) val += skp[(size_t)o * 196608];
        outp[(size_t)o * 196608] = val;
        if (DO_DFT) lds[o * 257 + m] = val;
    }
    if (DO_DFT) {
        __syncthreads();
        fold_lds(lds, m);
        __syncthreads();
        dft_row_phase(lds, tabF, Tout, b, v, n, m);
    }
}

// final: fc1v -> gelu -> fc1t (transposed rows, scalar reads) -> gelu -> fc2t
__global__ __launch_bounds__(256) void k_final(
    const float* __restrict__ IN, float* __restrict__ OUT,
    const float* __restrict__ w1v, const float* __restrict__ b1v,
    const float* __restrict__ w1tT, const float* __restrict__ b1t,
    const float* __restrict__ w2t, const float* __restrict__ b2t)
{
    int blk = blockIdx.x;            // (b*256 + n)*3 + vo
    int m = threadIdx.x;
    int vo = blk % 3; int rest = blk / 3;
    int n = rest & 255, b = rest >> 8;
    const float* inp = IN + (size_t)(b*96) * 65536 + n * 256 + m;

    float wv0 = w1v[vo], wv1 = w1v[3 + vo], wv2 = w1v[6 + vo], bv0 = b1v[vo];
    float Av[32];
#pragma unroll
    for (int c = 0; c < 32; c++) {
        float f0 = inp[(size_t)(c*3 + 0) * 65536];
        float f1 = inp[(size_t)(c*3 + 1) * 65536];
        float f2 = inp[(size_t)(c*3 + 2) * 65536];
        Av[c] = geluf(f0*wv0 + f1*wv1 + f2*wv2 + bv0);
    }

    float acc[10];
#pragma unroll
    for (int s = 0; s < 10; s++) acc[s] = 0.f;

#pragma unroll 4
    for (int u = 0; u < 256; u++) {
        float t = b1t[u];
#pragma unroll
        for (int c = 0; c < 32; c++) t = fmaf(Av[c], w1tT[u*32 + c], t);
        t = geluf(t);
#pragma unroll
        for (int s = 0; s < 10; s++) acc[s] = fmaf(t, w2t[u*10 + s], acc[s]);
    }

    float* outp = OUT + ((size_t)(b*3 + vo) * 65536 + (size_t)(n * 256 + m)) * 10;
#pragma unroll
    for (int s = 0; s < 10; s++) outp[s] = acc[s] + b2t[s];
}

extern "C" void kernel_launch(void* const* d_in, const int* in_sizes, int n_in,
                              void* d_out, int out_size, void* d_ws, size_t ws_size,
                              hipStream_t stream) {
    const float* x    = (const float*)d_in[0];
    const float* fc0w = (const float*)d_in[1];
    const float* fc0b = (const float*)d_in[2];
    const float* w1r  = (const float*)d_in[3];
    const float* w1i  = (const float*)d_in[4];
    const float* w2r  = (const float*)d_in[5];
    const float* w2i  = (const float*)d_in[6];
    const float* m1w  = (const float*)d_in[7];
    const float* m1b  = (const float*)d_in[8];
    const float* m2w  = (const float*)d_in[9];
    const float* m2b  = (const float*)d_in[10];
    const float* ww   = (const float*)d_in[11];
    const float* wb   = (const float*)d_in[12];
    const float* bw   = (const float*)d_in[13];
    const float* bb   = (const float*)d_in[14];
    const float* w1v  = (const float*)d_in[15];
    const float* b1v  = (const float*)d_in[16];
    const float* w1t  = (const float*)d_in[17];
    const float* b1t  = (const float*)d_in[18];
    const float* w2t  = (const float*)d_in[19];
    const float* b2t  = (const float*)d_in[20];

    float* ws   = (float*)d_ws;
    float* A    = ws + OFF_A;
    float* Bu   = ws + OFF_B;
    float* tabF = ws + OFF_T1;
    float* tab2 = ws + OFF_T2T;
    const float2* tcs = (const float2*)(ws + OFF_TCS);
    float* tbB  = ws + OFF_TB;
    float* w1tT = ws + OFF_WT;
    float2* fp1 = (float2*)(ws + OFF_FL);
    float2* fp2 = (float2*)(ws + OFF_FL + 1572864);

    float* dout = (float*)d_out;
    float* T    = dout + DO_T;
    float* T2B  = dout + DO_T2B;
    float* XFp  = dout + DO_XF;

    k_init_tables<<<64, 256, 0, stream>>>(ws, w1t);
    k_fc0<<<3072, 256, 0, stream>>>(x, fc0w, fc0b, A, T, tabF);

    // h0=L0(h) [A->A]; h=L1(h0) [A->B]; h=L2(h)+h0 [B->B, skip A];
    // h1=L3(h) [B->A]; h=L4(h1) [A->B]; h=L5(h)+h1 [B->B, skip A]
    float* lin [6] = {A, A, Bu, Bu, A, Bu};
    float* lout[6] = {A, Bu, Bu, A, Bu, Bu};
    const float* lskip[6] = {nullptr, nullptr, A, nullptr, nullptr, A};

    for (int l = 0; l < 6; l++) {
        k_foldw<<<1024, 256, 0, stream>>>(w1r + (size_t)l*786432, w1i + (size_t)l*786432,
                                          w2r + (size_t)l*786432, w2i + (size_t)l*786432,
                                          m1w + l*1024, fp1, fp2);
        k_dft_x<<<1536, 256, 0, stream>>>(T, XFp, tab2);
        k_mixidft<<<1536, 256, 0, stream>>>(XFp, T2B, fp1, fp2, tcs);
        int skip = lskip[l] != nullptr, dodft = (l < 5);
        if (skip && dodft)
            k_conv<1,1><<<3072, 256, 0, stream>>>(lin[l], lout[l], lskip[l], T2B, tbB,
                                                  m1b, m2w, m2b, ww, wb, bw, bb, T, tabF, l);
        else if (!skip && dodft)
            k_conv<0,1><<<3072, 256, 0, stream>>>(lin[l], lout[l], nullptr, T2B, tbB,
                                                  m1b, m2w, m2b, ww, wb, bw, bb, T, tabF, l);
        else if (skip && !dodft)
            k_conv<1,0><<<3072, 256, 0, stream>>>(lin[l], lout[l], lskip[l], T2B, tbB,
                                                  m1b, m2w, m2b, ww, wb, bw, bb, T, tabF, l);
        else
            k_conv<0,0><<<3072, 256, 0, stream>>>(lin[l], lout[l], nullptr, T2B, tbB,
                                                  m1b, m2w, m2b, ww, wb, bw, bb, T, tabF, l);
    }

    k_final<<<3072, 256, 0, stream>>>(Bu, dout, w1v, b1v, w1tT, b1t, w2t, b2t);
}

// Round 9
// 2366.825 us; speedup vs baseline: 1.1794x; 1.1794x over previous
//
#include <hip/hip_runtime.h>
#include <math.h>

// ---------------------------------------------------------------------------
// FNO_multi: B=4, V=3, S=256x256, TIN=10, WIDTH=32, M1=M2=16, NL=6, VOUT=3, STEP=10
// rfft2/irfft2 -> truncated DFT matmuls. All fp32. Base = R5 (best measured).
// R9 change: k_conv stages its per-block T2 row (4KB, block-unique data) into
// LDS via one coalesced float4 VMEM load per thread, instead of ~1024
// scalar-K$-missing uniform s_loads. Weight matrices stay s_load (K$-warm,
// proven by k_final's ~100% VALUBusy on the same pattern).
// Activations: [B][C=32][V][256][256].
// ---------------------------------------------------------------------------

#define OFF_A   0
#define OFF_B   25165824
#define OFF_T   50331648   // T / T2 shared buffer: [b][c][v][n][32]
#define OFF_XF  53477376   // 2 partial XF buffers, 393216 floats each
#define OFF_T1  54263808   // tabF [m=128][g=8][4]  (folded y-DFT tab)
#define OFF_T2T 54272000   // tab2 [n=256][kx=32][2] = (cos, sin)
#define OFF_TAC 54288384   // tabA_c [kx=32][n=256]
#define OFF_TAS 54296576   // tabA_s [kx=32][n=256]
#define OFF_TB  54304768   // tabB  [j=32][m=256]  (scaled inverse-y table)

// fast gelu: exact-erf form via A&S 7.1.26 (|eps_erf| <= ~1.5e-7)
__device__ __forceinline__ float geluf(float x) {
    float a = fabsf(x) * 0.70710678118654752f;
    float t = __builtin_amdgcn_rcpf(fmaf(0.3275911f, a, 1.0f));
    float p = t * fmaf(t, fmaf(t, fmaf(t, fmaf(t, 1.061405429f, -1.453152027f),
                                       1.421413741f), -0.284496736f), 0.254829592f);
    float e = __expf(-a * a);
    float erfa = fmaf(-p, e, 1.0f);
    float er = copysignf(erfa, x);
    return 0.5f * x * (1.0f + er);
}

__global__ void k_init_tables(float* __restrict__ ws) {
    const float W0 = 6.2831853071795864769f / 256.0f;
    int stride = gridDim.x * blockDim.x;
    int tid = blockIdx.x * blockDim.x + threadIdx.x;
    // tabF: folded forward y-DFT. group g: parity p=g>>2, idx=g&3; k0=4*idx+p, k1=k0+2
    for (int i = tid; i < 4096; i += stride) {
        int m = i >> 5, q = i & 31, g = q >> 2, j = q & 3;
        int k0 = 4 * (g & 3) + (g >> 2);
        int k = k0 + 2 * (j >> 1);
        float th = W0 * (float)((k * m) & 255);
        ws[OFF_T1 + i] = (j & 1) ? -sinf(th) : cosf(th);
    }
    for (int idx = tid; idx < 8192; idx += stride) {   // tab2
        int n = idx >> 5, kx = idx & 31;
        int KX = (kx < 16) ? kx : (kx + 224);
        float th = W0 * (float)((KX * n) & 255);
        ws[OFF_T2T + 2*idx]     = cosf(th);
        ws[OFF_T2T + 2*idx + 1] = sinf(th);
    }
    for (int idx = tid; idx < 8192; idx += stride) {   // tabA (inverse-x)
        int kx = idx >> 8, n = idx & 255;
        int KX = (kx < 16) ? kx : (kx + 224);
        float th = W0 * (float)((KX * n) & 255);
        ws[OFF_TAC + idx] = cosf(th);
        ws[OFF_TAS + idx] = sinf(th);
    }
    for (int idx = tid; idx < 8192; idx += stride) {   // tabB (inverse-y, scaled)
        int j = idx >> 8, m = idx & 255, k = j >> 1;
        float th = W0 * (float)((k * m) & 255);
        float beta = (k == 0) ? (1.0f/65536.0f) : (2.0f/65536.0f);
        float val;
        if (j & 1) val = (k == 0) ? 0.0f : -beta * sinf(th);
        else       val = beta * cosf(th);
        ws[OFF_TB + idx] = val;
    }
}

// radix-2 fold in LDS: row r: [0..127] <- x[m]+x[m+128]; [128..255] <- x[m]-x[m+128]
__device__ __forceinline__ void fold_lds(float* lds, int tid) {
#pragma unroll
    for (int it = 0; it < 16; ++it) {
        int pi = it * 256 + tid;
        int r = pi >> 7, mm = pi & 127;
        float* row = lds + r * 257;
        float a = row[mm], c = row[mm + 128];
        row[mm] = a + c; row[mm + 128] = a - c;
    }
}

// fused y-DFT phase: lds holds 32 folded rows (stride 257). Writes T rows (b,r,v,n).
__device__ __forceinline__ void dft_row_phase(const float* lds, const float* __restrict__ tabF,
                                              float* __restrict__ T, int b, int v, int n, int tid) {
    int r = tid >> 3, g = tid & 7;
    int p = g >> 2, idx = g & 3;
    const float* dp = lds + r * 257 + p * 128;
    const float* tp = tabF + g * 4;
    float a0 = 0.f, a1 = 0.f, a2 = 0.f, a3 = 0.f;
#pragma unroll 4
    for (int m = 0; m < 128; ++m) {
        float d = dp[m];
        float4 t = *(const float4*)(tp + m * 32);
        a0 += d * t.x; a1 += d * t.y; a2 += d * t.z; a3 += d * t.w;
    }
    size_t trow = ((size_t)((b * 32 + r) * 3 + v) * 256 + n) * 32;
    float2 w0; w0.x = a0; w0.y = a1;
    float2 w1; w1.x = a2; w1.y = a3;
    *(float2*)(T + trow + 8 * idx + 2 * p) = w0;      // k0 = 4*idx+p
    *(float2*)(T + trow + 8 * idx + 2 * p + 4) = w1;  // k1 = k0+2
}

// fc0 + fused y-DFT
__global__ __launch_bounds__(256) void k_fc0(const float* __restrict__ x,
                                             const float* __restrict__ w,
                                             const float* __restrict__ bias,
                                             float* __restrict__ outA,
                                             float* __restrict__ T,
                                             const float* __restrict__ tabF) {
    __shared__ float lds[32 * 257];
    int blk = blockIdx.x;           // (b*3+v)*256 + n
    int m = threadIdx.x;
    int n = blk & 255;
    int bv = blk >> 8;
    int v = bv % 3, b = bv / 3;
    const float* xp = x + ((size_t)blk * 256 + m) * 10;
    float xin[10];
#pragma unroll
    for (int t = 0; t < 10; t++) xin[t] = xp[t];
    float gx = (float)n * (1.0f/255.0f), gy = (float)m * (1.0f/255.0f);
    float* op = outA + ((size_t)(b*96) + v) * 65536 + n * 256 + m;
#pragma unroll
    for (int c = 0; c < 32; c++) {
        float a = bias[c] + gx * w[10*32 + c] + gy * w[11*32 + c];
#pragma unroll
        for (int t = 0; t < 10; t++) a += xin[t] * w[t*32 + c];
        op[(size_t)c * 196608] = a;
        lds[c * 257 + m] = a;
    }
    __syncthreads();
    fold_lds(lds, m);
    __syncthreads();
    dft_row_phase(lds, tabF, T, b, v, n, m);
}

// x-DFT, split 2-way over n.
__global__ __launch_bounds__(256) void k_dft_x(const float* __restrict__ T,
                                               float* __restrict__ XFp,
                                               const float* __restrict__ tab2) {
    __shared__ float lds[4096];
    int idx = blockIdx.x;
    int half = idx & 1; int blk = idx >> 1;   // blk = bv*32 + i
    int i = blk & 31; int bv = blk >> 5;
    int b = bv / 3, v = bv - 3*b;
    int tid = threadIdx.x;
    const float4* slab = (const float4*)(T + (size_t)((b*32 + i)*3 + v) * 8192 + half * 4096);
#pragma unroll
    for (int j = 0; j < 4; ++j)
        ((float4*)lds)[j * 256 + tid] = slab[j * 256 + tid];
    __syncthreads();
    int ky = tid & 15, kxh = tid >> 4;
    const float* t2b = tab2 + half * 128 * 64;
    float r0=0.f, i0=0.f, r1=0.f, i1=0.f;
#pragma unroll 2
    for (int nn = 0; nn < 128; nn++) {
        float2 t = *(const float2*)(lds + nn * 32 + 2 * ky);
        float2 cs0 = *(const float2*)(t2b + nn*64 + kxh*2);
        float2 cs1 = *(const float2*)(t2b + nn*64 + (kxh+16)*2);
        r0 += t.x*cs0.x + t.y*cs0.y;  i0 += t.y*cs0.x - t.x*cs0.y;
        r1 += t.x*cs1.x + t.y*cs1.y;  i1 += t.y*cs1.x - t.x*cs1.y;
    }
    float2* xfp = (float2*)(XFp + (size_t)(half * 384 + blk) * 1024);
    float2 v0; v0.x = r0; v0.y = i0;
    float2 v1; v1.x = r1; v1.y = i1;
    xfp[kxh*16 + ky] = v0;
    xfp[(kxh+16)*16 + ky] = v1;
}

// channel mix (sums the 2 XF partials) + inverse x-DFT, split 2-way over n.
__global__ __launch_bounds__(256) void k_mixidft(const float* __restrict__ XFp,
                                                 float* __restrict__ T2,
                                                 const float* __restrict__ w1r,
                                                 const float* __restrict__ w1i,
                                                 const float* __restrict__ w2r,
                                                 const float* __restrict__ w2i,
                                                 const float* __restrict__ tac,
                                                 const float* __restrict__ tas, int l) {
    __shared__ float Olds[2048];
    int idx = blockIdx.x;
    int half = idx & 1; int blk = idx >> 1;   // blk = bv*32 + o
    int o = blk & 31; int bv = blk >> 5;
    int b = bv / 3, v = bv - 3*b;
    int tid = threadIdx.x;
    {
        int ky = tid & 15, kxh = tid >> 4;
        float R0=0.f, I0=0.f, R1=0.f, I1=0.f;
#pragma unroll
        for (int i = 0; i < 32; i++) {
            const float2* xa = (const float2*)(XFp + (size_t)(bv*32 + i) * 1024);
            const float2* xb = (const float2*)(XFp + (size_t)(384 + bv*32 + i) * 1024);
            float2 p0 = xa[kxh*16 + ky], q0 = xb[kxh*16 + ky];
            float2 p1 = xa[(kxh+16)*16 + ky], q1 = xb[(kxh+16)*16 + ky];
            float2 xf0; xf0.x = p0.x + q0.x; xf0.y = p0.y + q0.y;
            float2 xf1; xf1.x = p1.x + q1.x; xf1.y = p1.y + q1.y;
            size_t wbase = ((size_t)((l*32 + i)*32 + o)*3 + v) * 256;
            float a1r = w1r[wbase + tid], a1i = w1i[wbase + tid];
            float a2r = w2r[wbase + tid], a2i = w2i[wbase + tid];
            R0 += xf0.x*a1r - xf0.y*a1i;  I0 += xf0.x*a1i + xf0.y*a1r;
            R1 += xf1.x*a2r - xf1.y*a2i;  I1 += xf1.x*a2i + xf1.y*a2r;
        }
        float2 v0; v0.x = R0; v0.y = I0;
        float2 v1; v1.x = R1; v1.y = I1;
        ((float2*)Olds)[kxh*16 + ky] = v0;
        ((float2*)Olds)[(kxh+16)*16 + ky] = v1;
    }
    __syncthreads();
    {
        int ky2 = tid & 31, n8 = tid >> 5;
        int ky = ky2 >> 1, ri = ky2 & 1;
        float* t2p = T2 + (size_t)((b*32 + o)*3 + v) * 8192;
#pragma unroll 2
        for (int ii = 0; ii < 16; ++ii) {
            int n = half * 128 + ii*8 + n8;
            float acc = 0.f;
#pragma unroll
            for (int kx = 0; kx < 32; ++kx) {
                float2 ov = ((const float2*)Olds)[kx*16 + ky];
                float c = tac[kx*256 + n], s = tas[kx*256 + n];
                float ca = ri ? s : c;
                float cb = ri ? c : -s;
                acc += ov.x*ca + ov.y*cb;
            }
            t2p[n*32 + ky2] = acc;
        }
    }
}

// fused: inverse y-DFT (T2 row staged to LDS) + m1 + gelu + m2/ww conv
// + optional skip + fused next-layer y-DFT.
// T2 row is block-unique -> uniform s_loads would K$-miss; stage via one
// coalesced float4 VMEM load/thread, consume via broadcast ds_read_b128.
template<int HAS_SKIP, int DO_DFT>
__global__ __launch_bounds__(256) void k_conv(
    const float* IN, float* OUT, const float* SK,
    const float* __restrict__ T2, const float* __restrict__ tabB,
    const float* __restrict__ m1w, const float* __restrict__ m1b,
    const float* __restrict__ m2w, const float* __restrict__ m2b,
    const float* __restrict__ ww,  const float* __restrict__ wb,
    const float* __restrict__ bw,  const float* __restrict__ bb,
    float* __restrict__ Tout, const float* __restrict__ tabF, int l)
{
    __shared__ float t2s[1024];              // [c][j] staged T2 row
    __shared__ float lds[DO_DFT ? 32 * 257 : 1];
    int blk = blockIdx.x;            // (b*3+v)*256 + n
    int m = threadIdx.x;
    int n = blk & 255; int bv = blk >> 8;
    int b = bv / 3, v = bv - 3*b;

    // ---- cooperative stage: thread m loads float4 of T2[b, c=m>>3, v, n, (m&7)*4]
    {
        int c = m >> 3, q = m & 7;
        const float4* src = (const float4*)(T2 + (size_t)b * 786432 + (size_t)c * 24576
                                            + v * 8192 + n * 32 + q * 4);
        ((float4*)t2s)[m] = *src;
    }
    // ---- tb (per-thread inverse-y column)
    float tb[32];
#pragma unroll
    for (int j = 0; j < 32; j++) tb[j] = tabB[j*256 + m];
    __syncthreads();

    // ---- issue h loads (x2 path); latency hides under Phase A/B compute
    const float* inp = IN + (size_t)(b*96 + v) * 65536 + n * 256 + m;
    float hv[32];
#pragma unroll
    for (int c = 0; c < 32; c++) hv[c] = inp[(size_t)c * 196608];

    // ---- Phase A: inverse y-DFT from LDS (broadcast reads)
    float x1[32];
#pragma unroll
    for (int c = 0; c < 32; c++) {
        const float4* q = (const float4*)(t2s + c*32);
        float a = 0.f;
#pragma unroll
        for (int jj = 0; jj < 8; jj++) {
            float4 qv = q[jj];
            a = fmaf(qv.x, tb[jj*4+0], a);
            a = fmaf(qv.y, tb[jj*4+1], a);
            a = fmaf(qv.z, tb[jj*4+2], a);
            a = fmaf(qv.w, tb[jj*4+3], a);
        }
        x1[c] = a;
    }

    // ---- Phase B: m1 + gelu (m1w is layer-constant: K$-warm s_loads)
    const float* m1wl = m1w + l*1024; const float* m1bl = m1b + l*32;
    float g1[32];
#pragma unroll
    for (int o = 0; o < 32; o++) {
        float a = m1bl[o];
#pragma unroll
        for (int c = 0; c < 32; c++) a = fmaf(m1wl[o*32 + c], x1[c], a);
        g1[o] = geluf(a);
    }

    // ---- Phase C: per-o m2.g1 + ww.hv + bias, gelu, store (+DFT stage)
    const float* m2wl = m2w + l*1024; const float* m2bl = m2b + l*32;
    const float* wwl  = ww  + l*1024; const float* wbl  = wb  + l*32;
    const float* bwl  = bw  + l*64;   const float* bbl  = bb  + l*32;
    float gx = (float)n * (1.0f/255.0f), gy = (float)m * (1.0f/255.0f);
    float* outp = OUT + (size_t)(b*96 + v) * 65536 + n * 256 + m;
    const float* skp = SK + (size_t)(b*96 + v) * 65536 + n * 256 + m;

#pragma unroll
    for (int o = 0; o < 32; o++) {
        float a = m2bl[o] + wbl[o] + bbl[o] + bwl[o*2]*gx + bwl[o*2+1]*gy;
#pragma unroll
        for (int c = 0; c < 32; c++) a = fmaf(m2wl[o*32 + c], g1[c], a);
#pragma unroll
        for (int c = 0; c < 32; c++) a = fmaf(wwl[o*32 + c], hv[c], a);
        float val = geluf(a);
        if (HAS_SKIP) val += skp[(size_t)o * 196608];
        outp[(size_t)o * 196608] = val;
        if (DO_DFT) lds[o * 257 + m] = val;
    }
    if (DO_DFT) {
        __syncthreads();
        fold_lds(lds, m);
        __syncthreads();
        dft_row_phase(lds, tabF, Tout, b, v, n, m);
    }
}

// final: fc1v (v->vout, gelu) -> fc1t (32->256, gelu) -> fc2t (256->10); per-vo split
__global__ __launch_bounds__(256) void k_final(
    const float* __restrict__ IN, float* __restrict__ OUT,
    const float* __restrict__ w1v, const float* __restrict__ b1v,
    const float* __restrict__ w1t, const float* __restrict__ b1t,
    const float* __restrict__ w2t, const float* __restrict__ b2t)
{
    int blk = blockIdx.x;            // (b*256 + n)*3 + vo
    int m = threadIdx.x;
    int vo = blk % 3; int rest = blk / 3;
    int n = rest & 255, b = rest >> 8;
    const float* inp = IN + (size_t)(b*96) * 65536 + n * 256 + m;

    float wv0 = w1v[vo], wv1 = w1v[3 + vo], wv2 = w1v[6 + vo], bv0 = b1v[vo];
    float Av[32];
#pragma unroll
    for (int c = 0; c < 32; c++) {
        float f0 = inp[(size_t)(c*3 + 0) * 65536];
        float f1 = inp[(size_t)(c*3 + 1) * 65536];
        float f2 = inp[(size_t)(c*3 + 2) * 65536];
        Av[c] = geluf(f0*wv0 + f1*wv1 + f2*wv2 + bv0);
    }

    float acc[10];
#pragma unroll
    for (int s = 0; s < 10; s++) acc[s] = 0.f;

#pragma unroll 4
    for (int u = 0; u < 256; u++) {
        float t = b1t[u];
#pragma unroll
        for (int c = 0; c < 32; c++) t = fmaf(Av[c], w1t[c*256 + u], t);
        t = geluf(t);
#pragma unroll
        for (int s = 0; s < 10; s++) acc[s] = fmaf(t, w2t[u*10 + s], acc[s]);
    }

    float* outp = OUT + ((size_t)(b*3 + vo) * 65536 + (size_t)(n * 256 + m)) * 10;
#pragma unroll
    for (int s = 0; s < 10; s++) outp[s] = acc[s] + b2t[s];
}

extern "C" void kernel_launch(void* const* d_in, const int* in_sizes, int n_in,
                              void* d_out, int out_size, void* d_ws, size_t ws_size,
                              hipStream_t stream) {
    const float* x    = (const float*)d_in[0];
    const float* fc0w = (const float*)d_in[1];
    const float* fc0b = (const float*)d_in[2];
    const float* w1r  = (const float*)d_in[3];
    const float* w1i  = (const float*)d_in[4];
    const float* w2r  = (const float*)d_in[5];
    const float* w2i  = (const float*)d_in[6];
    const float* m1w  = (const float*)d_in[7];
    const float* m1b  = (const float*)d_in[8];
    const float* m2w  = (const float*)d_in[9];
    const float* m2b  = (const float*)d_in[10];
    const float* ww   = (const float*)d_in[11];
    const float* wb   = (const float*)d_in[12];
    const float* bw   = (const float*)d_in[13];
    const float* bb   = (const float*)d_in[14];
    const float* w1v  = (const float*)d_in[15];
    const float* b1v  = (const float*)d_in[16];
    const float* w1t  = (const float*)d_in[17];
    const float* b1t  = (const float*)d_in[18];
    const float* w2t  = (const float*)d_in[19];
    const float* b2t  = (const float*)d_in[20];

    float* ws   = (float*)d_ws;
    float* A    = ws + OFF_A;
    float* Bu   = ws + OFF_B;
    float* T    = ws + OFF_T;
    float* XFp  = ws + OFF_XF;
    float* tabF = ws + OFF_T1;
    float* tab2 = ws + OFF_T2T;
    float* tac  = ws + OFF_TAC;
    float* tas  = ws + OFF_TAS;
    float* tbB  = ws + OFF_TB;

    k_init_tables<<<64, 256, 0, stream>>>(ws);
    k_fc0<<<3072, 256, 0, stream>>>(x, fc0w, fc0b, A, T, tabF);

    // h0=L0(h) [A->A]; h=L1(h0) [A->B]; h=L2(h)+h0 [B->B, skip A];
    // h1=L3(h) [B->A]; h=L4(h1) [A->B]; h=L5(h)+h1 [B->B, skip A]
    float* lin [6] = {A, A, Bu, Bu, A, Bu};
    float* lout[6] = {A, Bu, Bu, A, Bu, Bu};
    const float* lskip[6] = {nullptr, nullptr, A, nullptr, nullptr, A};

    for (int l = 0; l < 6; l++) {
        k_dft_x<<<768, 256, 0, stream>>>(T, XFp, tab2);
        k_mixidft<<<768, 256, 0, stream>>>(XFp, T, w1r, w1i, w2r, w2i, tac, tas, l);
        int skip = lskip[l] != nullptr, dodft = (l < 5);
        if (skip && dodft)
            k_conv<1,1><<<3072, 256, 0, stream>>>(lin[l], lout[l], lskip[l], T, tbB,
                                                  m1w, m1b, m2w, m2b, ww, wb, bw, bb, T, tabF, l);
        else if (!skip && dodft)
            k_conv<0,1><<<3072, 256, 0, stream>>>(lin[l], lout[l], nullptr, T, tbB,
                                                  m1w, m1b, m2w, m2b, ww, wb, bw, bb, T, tabF, l);
        else if (skip && !dodft)
            k_conv<1,0><<<3072, 256, 0, stream>>>(lin[l], lout[l], lskip[l], T, tbB,
                                                  m1w, m1b, m2w, m2b, ww, wb, bw, bb, T, tabF, l);
        else
            k_conv<0,0><<<3072, 256, 0, stream>>>(lin[l], lout[l], nullptr, T, tbB,
                                                  m1w, m1b, m2w, m2b, ww, wb, bw, bb, T, tabF, l);
    }

    k_final<<<3072, 256, 0, stream>>>(Bu, (float*)d_out, w1v, b1v, w1t, b1t, w2t, b2t);
}